// Round 6
// baseline (166.869 us; speedup 1.0000x reference)
//
#include <hip/hip_runtime.h>
#include <stdint.h>

// B=8, N=1024, I=256, O=256, R=8
// out[b,dst,o] = (sum_{src,r} adj[b,src,dst,r] * f[b,src,r,o]) / clip(sum adj, 1e-16)
//
//  prep   : x fp32->bf16 [8192][256]; weight[r][i][o] -> W_t[o*8+r][i] bf16
//  k1     : f_t[b][o][k=src*8+r] = W_t @ x^T (8B vector stores)
//  k2     : out = (adj^T @ f_t)/denom fully fused. 1024 blocks x 256 thr (4 waves),
//           MT=32 dst x NT=64 o, full K (128 kt x 8 src x 8 r). 4 blocks/CU ->
//           4 independent barrier domains (TLP hides vmem latency, m114).
//           bid = [dst(5)|o(2)|b(3)]: 4 o-tile blocks of one dst-tile co-dispatch
//           on one XCD -> adj L2 multicast; f_t[b]=4MB resident in XCD L2.
//           2-buffer issue-early LDS loop; fused fp32 denom + normalize.

typedef float          floatx4  __attribute__((ext_vector_type(4)));
typedef short          shortx8  __attribute__((ext_vector_type(8)));
typedef unsigned short ushortx4 __attribute__((ext_vector_type(4)));
typedef unsigned short ushortx8 __attribute__((ext_vector_type(8)));

__device__ __forceinline__ unsigned short f2bf(float f) {
  union { float f; unsigned int u; } v; v.f = f;
  unsigned int u = v.u + 0x7FFFu + ((v.u >> 16) & 1u);  // RNE
  return (unsigned short)(u >> 16);
}

__device__ __forceinline__ void gload16(const void* g, void* l) {
  __builtin_amdgcn_global_load_lds((__attribute__((address_space(1))) void*)g,
                                   (__attribute__((address_space(3))) void*)l,
                                   16, 0, 0);
}

// ---------------- merged prep ----------------
__global__ __launch_bounds__(256) void prep_xw(const float* __restrict__ x,
                                               const float* __restrict__ w,
                                               unsigned short* __restrict__ xbf,
                                               unsigned short* __restrict__ wt) {
  int bid = blockIdx.x;
  if (bid < 1024) {                                // x: 262144 threads x 8 elems
    int t = bid * 256 + threadIdx.x;
    const float4* p = (const float4*)x + (size_t)t * 2;
    float4 a = p[0], b4 = p[1];
    ushortx8 o;
    o[0] = f2bf(a.x);  o[1] = f2bf(a.y);  o[2] = f2bf(a.z);  o[3] = f2bf(a.w);
    o[4] = f2bf(b4.x); o[5] = f2bf(b4.y); o[6] = f2bf(b4.z); o[7] = f2bf(b4.w);
    *(ushortx8*)(xbf + (size_t)t * 8) = o;
  } else {                                         // w: 524288 scalar
    int id = (bid - 1024) * 256 + threadIdx.x;
    int r = id >> 16, i = (id >> 8) & 255, o = id & 255;
    float v = w[((size_t)(r * 256 + i) << 8) + o];
    wt[((size_t)(o * 8 + r) << 8) + i] = f2bf(v);
  }
}

// ---------------- kernel 1: f_t = x @ W (operand-swapped) ----------------
__global__ __launch_bounds__(256) void k1_gemm(const unsigned short* __restrict__ xbf,
                                               const unsigned short* __restrict__ wt,
                                               unsigned short* __restrict__ ft) {
  int bid = blockIdx.x;                            // 16 p-tiles x 64 q-tiles
  int p0 = (bid & 15) * 128, q0 = (bid >> 4) * 128;
  int l = threadIdx.x & 63, w = threadIdx.x >> 6;
  int lr = l & 15, lg = l >> 4;
  int pw = p0 + (w >> 1) * 64, qw = q0 + (w & 1) * 64;

  floatx4 acc[4][4] = {};
#pragma unroll
  for (int ks = 0; ks < 8; ++ks) {                 // K = 256 = 8 * 32
    shortx8 a[4], b[4];
#pragma unroll
    for (int pi = 0; pi < 4; ++pi)
      a[pi] = *(const shortx8*)(wt + (size_t)(pw + pi * 16 + lr) * 256 + ks * 32 + lg * 8);
#pragma unroll
    for (int qi = 0; qi < 4; ++qi)
      b[qi] = *(const shortx8*)(xbf + (size_t)(qw + qi * 16 + lr) * 256 + ks * 32 + lg * 8);
#pragma unroll
    for (int pi = 0; pi < 4; ++pi)
#pragma unroll
      for (int qi = 0; qi < 4; ++qi)
        acc[pi][qi] = __builtin_amdgcn_mfma_f32_16x16x32_bf16(a[pi], b[qi], acc[pi][qi], 0, 0, 0);
  }
  // row(n') = pw+pi*16+lg*4+reg -> (o, r); col(m) = qw+qi*16+lr -> (b8, src)
#pragma unroll
  for (int pi = 0; pi < 4; ++pi) {
    int nbase = pw + pi * 16 + lg * 4;
    int o = nbase >> 3, rb = nbase & 7;
#pragma unroll
    for (int qi = 0; qi < 4; ++qi) {
      int m = qw + qi * 16 + lr;
      int b8 = m >> 10, src = m & 1023;
      ushortx4 h;
      h[0] = f2bf(acc[pi][qi][0]); h[1] = f2bf(acc[pi][qi][1]);
      h[2] = f2bf(acc[pi][qi][2]); h[3] = f2bf(acc[pi][qi][3]);
      *(ushortx4*)(ft + ((size_t)(b8 * 256 + o) << 13) + src * 8 + rb) = h;
    }
  }
}

// ---------------- kernel 2: out = (adj^T @ f_t)/denom, fully fused ----------------
// 1024 blocks x 256 thr (4 waves). Block: batch b, 32 dst, 64 o, full K.
#define BSZ (64 * 64)     // shorts per B buffer (8KB)
#define ASZ (32 * 64)     // shorts per A buffer (4KB)
#define NKT 128
__global__ __launch_bounds__(256, 4) void k2_gemm(const float* __restrict__ adj,
                                                  const unsigned short* __restrict__ ft,
                                                  float* __restrict__ outp) {
  __shared__ __align__(16) unsigned short Blds[2 * BSZ];  // 16KB
  __shared__ __align__(16) unsigned short Alds[2 * ASZ];  // 8KB (overlaid post-loop)

  int bid = blockIdx.x;
  int b = bid & 7;                    // XCD pin (adj[b] + f_t[b] traffic stays on XCD b)
  int o0 = ((bid >> 3) & 3) * 64;     // o-tile: fastest above b -> 4 sharers co-dispatch
  int dst0 = (bid >> 5) * 32;

  int t = threadIdx.x, l = t & 63, w = t >> 6;     // 4 waves, wave = 16-o slice
  int lr = l & 15, lg = l >> 4;

  // A-staging: thread -> dst_l (0..31), r-half, 2 src rows (w, w+4)
  int dst_l = l >> 1;
  int rh = (l & 1) * 4;
  // B-staging: pre-swizzled source chunk
  int csw = (l & 7) ^ (l >> 3);

  const size_t adj_b = (size_t)b << 23;
  const unsigned short* ftb = ft + ((size_t)b << 21);

  float dsum = 0.f;
  floatx4 acc[2] = {};
  float4 av[2];

  auto A_load = [&](int kt, float4* v) {
#pragma unroll
    for (int j = 0; j < 2; ++j) {
      int src = kt * 8 + w + j * 4;
      v[j] = *(const float4*)(adj + adj_b + ((size_t)src << 13)
                              + ((size_t)(dst0 + dst_l) << 3) + rh);
    }
  };
  auto A_store = [&](int buf, const float4* v) {
#pragma unroll
    for (int j = 0; j < 2; ++j) {
      int src_l = w + j * 4;
      float4 q = v[j];
      dsum += q.x + q.y + q.z + q.w;
      ushortx4 h;
      h[0] = f2bf(q.x); h[1] = f2bf(q.y); h[2] = f2bf(q.z); h[3] = f2bf(q.w);
      int slot = src_l ^ (dst_l & 7);
      *(ushortx4*)&Alds[buf * ASZ + dst_l * 64 + slot * 8 + rh] = h;
    }
  };
  auto B_stage = [&](int kt, int buf) {            // 2 gload16/wave, 64 o-rows total
    int kbase = kt * 64;
#pragma unroll
    for (int i = 0; i < 2; ++i) {
      int orow = w * 16 + i * 8 + (l >> 3);        // local o row
      const unsigned short* g = ftb + ((size_t)(o0 + orow) << 13) + kbase + (csw << 3);
      gload16(g, &Blds[buf * BSZ + (w * 16 + i * 8) * 64]);
    }
  };
  auto compute = [&](int buf) {
#pragma unroll
    for (int s = 0; s < 2; ++s) {
      int slotbase = s * 4 + lg;
      shortx8 af[2];
#pragma unroll
      for (int mi = 0; mi < 2; ++mi) {
        int arow = mi * 16 + lr;
        af[mi] = *(const shortx8*)&Alds[buf * ASZ + arow * 64 + ((slotbase ^ (arow & 7)) << 3)];
      }
      int brow = w * 16 + lr;                      // local o row
      shortx8 bfr = *(const shortx8*)&Blds[buf * BSZ + brow * 64 + ((slotbase ^ (lr & 7)) << 3)];
#pragma unroll
      for (int mi = 0; mi < 2; ++mi)
        acc[mi] = __builtin_amdgcn_mfma_f32_16x16x32_bf16(af[mi], bfr, acc[mi], 0, 0, 0);
    }
  };

  // ---- prologue: stage kt=0 into buf 0 ----
  A_load(0, av);
  B_stage(0, 0);
  A_store(0, av);
  __syncthreads();

  // ---- main loop: 2-buffer, issue-early; 4 blocks/CU cover the drains ----
  for (int kt = 0; kt < NKT; ++kt) {
    int cur = kt & 1, nxt = cur ^ 1;
    bool has = (kt + 1) < NKT;
    if (has) { A_load(kt + 1, av); B_stage(kt + 1, nxt); }
    compute(cur);
    if (has) A_store(nxt, av);
    __syncthreads();
  }

  // ---- denom reduction (deterministic), overlaid in Alds ----
  float* dsf = (float*)Alds;
  dsf[t] = dsum;
  __syncthreads();
  if (t < 32) {
    float s = 0.f;
#pragma unroll
    for (int sl = 0; sl < 4; ++sl) {
      s += dsf[sl * 64 + t * 2];
      s += dsf[sl * 64 + t * 2 + 1];
    }
    dsf[256 + t] = s;
  }
  __syncthreads();

  // ---- fused normalize + write (64-o slice) ----
#pragma unroll
  for (int mi = 0; mi < 2; ++mi) {
#pragma unroll
    for (int reg = 0; reg < 4; ++reg) {
      int rowl = mi * 16 + lg * 4 + reg;
      float dinv = 1.f / fmaxf(dsf[256 + rowl], 1e-16f);
      int row = dst0 + rowl;
      int col = o0 + w * 16 + lr;
      outp[(((size_t)b << 10) + row) * 256 + col] = acc[mi][reg] * dinv;
    }
  }
}

// ---------------- launch ----------------
extern "C" void kernel_launch(void* const* d_in, const int* in_sizes, int n_in,
                              void* d_out, int out_size, void* d_ws, size_t ws_size,
                              hipStream_t stream) {
  const float* x   = (const float*)d_in[0];
  const float* adj = (const float*)d_in[1];
  const float* w   = (const float*)d_in[2];
  float* out = (float*)d_out;

  char* ws = (char*)d_ws;
  unsigned short* ft  = (unsigned short*)(ws);              // 32 MB
  unsigned short* xbf = (unsigned short*)(ws + 33554432);   //  4 MB
  unsigned short* wt  = (unsigned short*)(ws + 37748736);   //  1 MB

  prep_xw<<<3072, 256, 0, stream>>>(x, w, xbf, wt);
  k1_gemm<<<1024, 256, 0, stream>>>(xbf, wt, ft);
  k2_gemm<<<1024, 256, 0, stream>>>(adj, ft, out);
}

// Round 7
// 161.927 us; speedup vs baseline: 1.0305x; 1.0305x over previous
//
#include <hip/hip_runtime.h>
#include <stdint.h>

// B=8, N=1024, I=256, O=256, R=8
// out[b,dst,o] = (sum_{src,r} adj[b,src,dst,r] * f[b,src,r,o]) / clip(sum adj, 1e-16)
//
//  prep   : x fp32->bf16 [8192][256]; weight[r][i][o] -> W_t[o*8+r][i] bf16
//  k1     : f_t[b][o][k=src*8+r] = W_t @ x^T (8B vector stores)
//  k2     : out = (adj^T @ f_t)/denom fused. 1024 blocks x 256 thr (4 waves),
//           MT=32 dst x NT=64 o, full K (128 kt x 8 src x 8 r). 4 blocks/CU.
//           R6->R7: 3-buffer pipeline with COUNTED vmcnt(4) across the barrier
//           (T3/T4, m201 fence pattern) — A(kt+2)+B(kt+2) stay in flight, so the
//           per-kt barrier no longer drains to zero (R6 measured 2890 cyc/kt from
//           vmcnt(0) tail-latency drains; catalog m218: counted-vs-drain0 +38-73%).

typedef float          floatx4  __attribute__((ext_vector_type(4)));
typedef short          shortx8  __attribute__((ext_vector_type(8)));
typedef unsigned short ushortx4 __attribute__((ext_vector_type(4)));
typedef unsigned short ushortx8 __attribute__((ext_vector_type(8)));

__device__ __forceinline__ unsigned short f2bf(float f) {
  union { float f; unsigned int u; } v; v.f = f;
  unsigned int u = v.u + 0x7FFFu + ((v.u >> 16) & 1u);  // RNE
  return (unsigned short)(u >> 16);
}

__device__ __forceinline__ void gload16(const void* g, void* l) {
  __builtin_amdgcn_global_load_lds((__attribute__((address_space(1))) void*)g,
                                   (__attribute__((address_space(3))) void*)l,
                                   16, 0, 0);
}

#define FENCE_KEEP4 asm volatile("s_waitcnt vmcnt(4) lgkmcnt(0)" ::: "memory")
#define FENCE_ALL   asm volatile("s_waitcnt vmcnt(0) lgkmcnt(0)" ::: "memory")
#define MEMFENCE    asm volatile("" ::: "memory")

// ---------------- merged prep ----------------
__global__ __launch_bounds__(256) void prep_xw(const float* __restrict__ x,
                                               const float* __restrict__ w,
                                               unsigned short* __restrict__ xbf,
                                               unsigned short* __restrict__ wt) {
  int bid = blockIdx.x;
  if (bid < 1024) {                                // x: 262144 threads x 8 elems
    int t = bid * 256 + threadIdx.x;
    const float4* p = (const float4*)x + (size_t)t * 2;
    float4 a = p[0], b4 = p[1];
    ushortx8 o;
    o[0] = f2bf(a.x);  o[1] = f2bf(a.y);  o[2] = f2bf(a.z);  o[3] = f2bf(a.w);
    o[4] = f2bf(b4.x); o[5] = f2bf(b4.y); o[6] = f2bf(b4.z); o[7] = f2bf(b4.w);
    *(ushortx8*)(xbf + (size_t)t * 8) = o;
  } else {                                         // w: 524288 scalar
    int id = (bid - 1024) * 256 + threadIdx.x;
    int r = id >> 16, i = (id >> 8) & 255, o = id & 255;
    float v = w[((size_t)(r * 256 + i) << 8) + o];
    wt[((size_t)(o * 8 + r) << 8) + i] = f2bf(v);
  }
}

// ---------------- kernel 1: f_t = x @ W (operand-swapped) ----------------
__global__ __launch_bounds__(256) void k1_gemm(const unsigned short* __restrict__ xbf,
                                               const unsigned short* __restrict__ wt,
                                               unsigned short* __restrict__ ft) {
  int bid = blockIdx.x;                            // 16 p-tiles x 64 q-tiles
  int p0 = (bid & 15) * 128, q0 = (bid >> 4) * 128;
  int l = threadIdx.x & 63, w = threadIdx.x >> 6;
  int lr = l & 15, lg = l >> 4;
  int pw = p0 + (w >> 1) * 64, qw = q0 + (w & 1) * 64;

  floatx4 acc[4][4] = {};
#pragma unroll
  for (int ks = 0; ks < 8; ++ks) {                 // K = 256 = 8 * 32
    shortx8 a[4], b[4];
#pragma unroll
    for (int pi = 0; pi < 4; ++pi)
      a[pi] = *(const shortx8*)(wt + (size_t)(pw + pi * 16 + lr) * 256 + ks * 32 + lg * 8);
#pragma unroll
    for (int qi = 0; qi < 4; ++qi)
      b[qi] = *(const shortx8*)(xbf + (size_t)(qw + qi * 16 + lr) * 256 + ks * 32 + lg * 8);
#pragma unroll
    for (int pi = 0; pi < 4; ++pi)
#pragma unroll
      for (int qi = 0; qi < 4; ++qi)
        acc[pi][qi] = __builtin_amdgcn_mfma_f32_16x16x32_bf16(a[pi], b[qi], acc[pi][qi], 0, 0, 0);
  }
  // row(n') = pw+pi*16+lg*4+reg -> (o, r); col(m) = qw+qi*16+lr -> (b8, src)
#pragma unroll
  for (int pi = 0; pi < 4; ++pi) {
    int nbase = pw + pi * 16 + lg * 4;
    int o = nbase >> 3, rb = nbase & 7;
#pragma unroll
    for (int qi = 0; qi < 4; ++qi) {
      int m = qw + qi * 16 + lr;
      int b8 = m >> 10, src = m & 1023;
      ushortx4 h;
      h[0] = f2bf(acc[pi][qi][0]); h[1] = f2bf(acc[pi][qi][1]);
      h[2] = f2bf(acc[pi][qi][2]); h[3] = f2bf(acc[pi][qi][3]);
      *(ushortx4*)(ft + ((size_t)(b8 * 256 + o) << 13) + src * 8 + rb) = h;
    }
  }
}

// ---------------- kernel 2: out = (adj^T @ f_t)/denom, fully fused ----------------
// 1024 blocks x 256 thr (4 waves). Block: batch b, 32 dst, 64 o, full K.
// 3 LDS buffers, counted-vmcnt pipeline (depth 2).
#define BSZ (64 * 64)     // shorts per B buffer (8KB)
#define ASZ (32 * 64)     // shorts per A buffer (4KB)
#define NKT 128
__global__ __launch_bounds__(256, 4) void k2_gemm(const float* __restrict__ adj,
                                                  const unsigned short* __restrict__ ft,
                                                  float* __restrict__ outp) {
  __shared__ __align__(16) unsigned short Blds[3 * BSZ];  // 24KB
  __shared__ __align__(16) unsigned short Alds[3 * ASZ];  // 12KB (overlaid post-loop)

  int bid = blockIdx.x;
  int b = bid & 7;                    // XCD pin (adj[b] + f_t[b] traffic on XCD b)
  int o0 = ((bid >> 3) & 3) * 64;     // 4 o-sharers of one dst-tile co-dispatch
  int dst0 = (bid >> 5) * 32;

  int t = threadIdx.x, l = t & 63, w = t >> 6;     // 4 waves, wave = 16-o slice
  int lr = l & 15, lg = l >> 4;

  // A-staging: thread -> dst_l (0..31), r-half, 2 src rows (w, w+4)
  int dst_l = l >> 1;
  int rh = (l & 1) * 4;
  // B-staging: pre-swizzled source chunk
  int csw = (l & 7) ^ (l >> 3);

  const size_t adj_b = (size_t)b << 23;
  const unsigned short* ftb = ft + ((size_t)b << 21);

  float dsum = 0.f;
  floatx4 acc[2] = {};
  float4 avA[2], avB[2];

  auto A_load = [&](int kt, float4* v) {
#pragma unroll
    for (int j = 0; j < 2; ++j) {
      int src = kt * 8 + w + j * 4;
      v[j] = *(const float4*)(adj + adj_b + ((size_t)src << 13)
                              + ((size_t)(dst0 + dst_l) << 3) + rh);
    }
  };
  auto A_store = [&](int buf, const float4* v) {
#pragma unroll
    for (int j = 0; j < 2; ++j) {
      int src_l = w + j * 4;
      float4 q = v[j];
      dsum += q.x + q.y + q.z + q.w;
      ushortx4 h;
      h[0] = f2bf(q.x); h[1] = f2bf(q.y); h[2] = f2bf(q.z); h[3] = f2bf(q.w);
      int slot = src_l ^ (dst_l & 7);
      *(ushortx4*)&Alds[buf * ASZ + dst_l * 64 + slot * 8 + rh] = h;
    }
  };
  auto B_stage = [&](int kt, int buf) {            // 2 gload16/wave, own 16 o-rows
    int kbase = kt * 64;
#pragma unroll
    for (int i = 0; i < 2; ++i) {
      int orow = w * 16 + i * 8 + (l >> 3);
      const unsigned short* g = ftb + ((size_t)(o0 + orow) << 13) + kbase + (csw << 3);
      gload16(g, &Blds[buf * BSZ + (w * 16 + i * 8) * 64]);
    }
  };
  auto compute = [&](int buf) {
#pragma unroll
    for (int s = 0; s < 2; ++s) {
      int slotbase = s * 4 + lg;
      shortx8 af[2];
#pragma unroll
      for (int mi = 0; mi < 2; ++mi) {
        int arow = mi * 16 + lr;
        af[mi] = *(const shortx8*)&Alds[buf * ASZ + arow * 64 + ((slotbase ^ (arow & 7)) << 3)];
      }
      int brow = w * 16 + lr;
      shortx8 bfr = *(const shortx8*)&Blds[buf * BSZ + brow * 64 + ((slotbase ^ (lr & 7)) << 3)];
#pragma unroll
      for (int mi = 0; mi < 2; ++mi)
        acc[mi] = __builtin_amdgcn_mfma_f32_16x16x32_bf16(af[mi], bfr, acc[mi], 0, 0, 0);
    }
  };

  // ---- prologue: buf0 = kt0 (A stored, B staged); A(1),B(1) left in flight ----
  B_stage(0, 0);
  A_load(0, avA);
  A_load(1, avB);
  B_stage(1, 1);
  A_store(0, avA);                    // auto-waits A(0) (drains B(0) too; prologue-only)
  avA[0] = avB[0]; avA[1] = avB[1];
  FENCE_KEEP4;                        // keep A(1)+B(1) in flight
  __builtin_amdgcn_s_barrier();
  MEMFENCE;

  // ---- main loop: depth-2 counted-vmcnt pipeline, one barrier per kt ----
  int c0 = 0, c1 = 1, c2 = 2;
  for (int kt = 0; kt < NKT; ++kt) {
    bool iss = (kt + 2) < NKT;
    bool st  = (kt + 1) < NKT;
    if (iss) { A_load(kt + 2, avB); B_stage(kt + 2, c2); }
    if (st)  A_store(c1, avA);        // ds_write A(kt+1); auto-wait leaves B(kt+1)+new 4
    compute(c0);
    if (st) {
      if (iss) { FENCE_KEEP4; } else { FENCE_ALL; }  // B(kt+1) landed; kt+2 stays in flight
      __builtin_amdgcn_s_barrier();
      MEMFENCE;
    }
    avA[0] = avB[0]; avA[1] = avB[1];
    int tmp = c0; c0 = c1; c1 = c2; c2 = tmp;
  }
  __syncthreads();                    // protect Alds overlay (last iter has no barrier)

  // ---- denom reduction (deterministic), overlaid in Alds ----
  float* dsf = (float*)Alds;
  dsf[t] = dsum;
  __syncthreads();
  if (t < 32) {
    float s = 0.f;
#pragma unroll
    for (int sl = 0; sl < 4; ++sl) {
      s += dsf[sl * 64 + t * 2];
      s += dsf[sl * 64 + t * 2 + 1];
    }
    dsf[256 + t] = s;
  }
  __syncthreads();

  // ---- fused normalize + write (64-o slice) ----
#pragma unroll
  for (int mi = 0; mi < 2; ++mi) {
#pragma unroll
    for (int reg = 0; reg < 4; ++reg) {
      int rowl = mi * 16 + lg * 4 + reg;
      float dinv = 1.f / fmaxf(dsf[256 + rowl], 1e-16f);
      int row = dst0 + rowl;
      int col = o0 + w * 16 + lr;
      outp[(((size_t)b << 10) + row) * 256 + col] = acc[mi][reg] * dinv;
    }
  }
}

// ---------------- launch ----------------
extern "C" void kernel_launch(void* const* d_in, const int* in_sizes, int n_in,
                              void* d_out, int out_size, void* d_ws, size_t ws_size,
                              hipStream_t stream) {
  const float* x   = (const float*)d_in[0];
  const float* adj = (const float*)d_in[1];
  const float* w   = (const float*)d_in[2];
  float* out = (float*)d_out;

  char* ws = (char*)d_ws;
  unsigned short* ft  = (unsigned short*)(ws);              // 32 MB
  unsigned short* xbf = (unsigned short*)(ws + 33554432);   //  4 MB
  unsigned short* wt  = (unsigned short*)(ws + 37748736);   //  1 MB

  prep_xw<<<3072, 256, 0, stream>>>(x, w, xbf, wt);
  k1_gemm<<<1024, 256, 0, stream>>>(xbf, wt, ft);
  k2_gemm<<<1024, 256, 0, stream>>>(adj, ft, out);
}

// Round 8
// 136.994 us; speedup vs baseline: 1.2181x; 1.1820x over previous
//
#include <hip/hip_runtime.h>
#include <stdint.h>

// B=8, N=1024, I=256, O=256, R=8
// out[b,dst,o] = (sum_{src,r} adj[b,src,dst,r] * f[b,src,r,o]) / clip(sum adj, 1e-16)
//
//  prep : x fp32->bf16; weight -> W_t[o*8+r][i] bf16
//  k1   : f_t[b][o][k=src*8+r] = W_t @ x^T (8B vector stores)
//  k2   : pout = adj^T @ f_t. MT=64 dst x NT=128 o, KS=2 -> 512 blocks x 512 thr
//         (8 waves 2m x 4o), KT=64 (8 src), 2 blocks/CU (72KB LDS).
//         L2-side traffic 1.0 GB (adj 2x + f_t 16x) vs R6's 2 GB.
//         6-step-unrolled 3-buffer pipeline, compile-time buf indices + register
//         parity, counted s_waitcnt vmcnt(4): kt+2's 4 loads stay in flight
//         across the one barrier per kt. Fused fp32 denom.
//  k3   : sum split-K partials, normalize.

typedef float          floatx4  __attribute__((ext_vector_type(4)));
typedef short          shortx8  __attribute__((ext_vector_type(8)));
typedef unsigned short ushortx4 __attribute__((ext_vector_type(4)));
typedef unsigned short ushortx8 __attribute__((ext_vector_type(8)));

__device__ __forceinline__ unsigned short f2bf(float f) {
  union { float f; unsigned int u; } v; v.f = f;
  unsigned int u = v.u + 0x7FFFu + ((v.u >> 16) & 1u);  // RNE
  return (unsigned short)(u >> 16);
}

__device__ __forceinline__ void gload16(const void* g, void* l) {
  __builtin_amdgcn_global_load_lds((__attribute__((address_space(1))) void*)g,
                                   (__attribute__((address_space(3))) void*)l,
                                   16, 0, 0);
}

#define FENCE_KEEP4 asm volatile("s_waitcnt vmcnt(4) lgkmcnt(0)" ::: "memory")
#define FENCE_ALL   asm volatile("s_waitcnt vmcnt(0) lgkmcnt(0)" ::: "memory")
#define MEMFENCE    asm volatile("" ::: "memory")

// ---------------- merged prep ----------------
__global__ __launch_bounds__(256) void prep_xw(const float* __restrict__ x,
                                               const float* __restrict__ w,
                                               unsigned short* __restrict__ xbf,
                                               unsigned short* __restrict__ wt) {
  int bid = blockIdx.x;
  if (bid < 1024) {                                // x: 262144 threads x 8 elems
    int t = bid * 256 + threadIdx.x;
    const float4* p = (const float4*)x + (size_t)t * 2;
    float4 a = p[0], b4 = p[1];
    ushortx8 o;
    o[0] = f2bf(a.x);  o[1] = f2bf(a.y);  o[2] = f2bf(a.z);  o[3] = f2bf(a.w);
    o[4] = f2bf(b4.x); o[5] = f2bf(b4.y); o[6] = f2bf(b4.z); o[7] = f2bf(b4.w);
    *(ushortx8*)(xbf + (size_t)t * 8) = o;
  } else {                                         // w: 524288 scalar
    int id = (bid - 1024) * 256 + threadIdx.x;
    int r = id >> 16, i = (id >> 8) & 255, o = id & 255;
    float v = w[((size_t)(r * 256 + i) << 8) + o];
    wt[((size_t)(o * 8 + r) << 8) + i] = f2bf(v);
  }
}

// ---------------- kernel 1: f_t = x @ W (operand-swapped) ----------------
__global__ __launch_bounds__(256) void k1_gemm(const unsigned short* __restrict__ xbf,
                                               const unsigned short* __restrict__ wt,
                                               unsigned short* __restrict__ ft) {
  int bid = blockIdx.x;                            // 16 p-tiles x 64 q-tiles
  int p0 = (bid & 15) * 128, q0 = (bid >> 4) * 128;
  int l = threadIdx.x & 63, w = threadIdx.x >> 6;
  int lr = l & 15, lg = l >> 4;
  int pw = p0 + (w >> 1) * 64, qw = q0 + (w & 1) * 64;

  floatx4 acc[4][4] = {};
#pragma unroll
  for (int ks = 0; ks < 8; ++ks) {                 // K = 256 = 8 * 32
    shortx8 a[4], b[4];
#pragma unroll
    for (int pi = 0; pi < 4; ++pi)
      a[pi] = *(const shortx8*)(wt + (size_t)(pw + pi * 16 + lr) * 256 + ks * 32 + lg * 8);
#pragma unroll
    for (int qi = 0; qi < 4; ++qi)
      b[qi] = *(const shortx8*)(xbf + (size_t)(qw + qi * 16 + lr) * 256 + ks * 32 + lg * 8);
#pragma unroll
    for (int pi = 0; pi < 4; ++pi)
#pragma unroll
      for (int qi = 0; qi < 4; ++qi)
        acc[pi][qi] = __builtin_amdgcn_mfma_f32_16x16x32_bf16(a[pi], b[qi], acc[pi][qi], 0, 0, 0);
  }
  // row(n') = pw+pi*16+lg*4+reg -> (o, r); col(m) = qw+qi*16+lr -> (b8, src)
#pragma unroll
  for (int pi = 0; pi < 4; ++pi) {
    int nbase = pw + pi * 16 + lg * 4;
    int o = nbase >> 3, rb = nbase & 7;
#pragma unroll
    for (int qi = 0; qi < 4; ++qi) {
      int m = qw + qi * 16 + lr;
      int b8 = m >> 10, src = m & 1023;
      ushortx4 h;
      h[0] = f2bf(acc[pi][qi][0]); h[1] = f2bf(acc[pi][qi][1]);
      h[2] = f2bf(acc[pi][qi][2]); h[3] = f2bf(acc[pi][qi][3]);
      *(ushortx4*)(ft + ((size_t)(b8 * 256 + o) << 13) + src * 8 + rb) = h;
    }
  }
}

// ---------------- kernel 2: pout = adj^T @ f_t (+ denom) ----------------
// 512 blocks x 512 thr (8 waves, 2m x 4o). Block: b, 64 dst, 128 o, K-half.
#define ASZ (64 * 64)     // 8KB per A buffer
#define BSZ (128 * 64)    // 16KB per B buffer
__global__ __launch_bounds__(512, 4) void k2_gemm(const float* __restrict__ adj,
                                                  const unsigned short* __restrict__ ft,
                                                  float* __restrict__ pout,
                                                  float* __restrict__ dpart) {
  __shared__ __align__(16) unsigned short Alds[3 * ASZ];  // 24KB
  __shared__ __align__(16) unsigned short Blds[3 * BSZ];  // 48KB

  int bid = blockIdx.x;
  int b = bid & 7;                     // XCD pin
  int o0 = ((bid >> 3) & 1) * 128;     // 2 o-tiles
  int kc = (bid >> 4) & 1;             // split-K half
  int dst0 = (bid >> 5) * 64;          // 16 dst-tiles

  int t = threadIdx.x, l = t & 63, w = t >> 6;     // 8 waves
  int lr = l & 15, lg = l >> 4;
  int wm = w >> 2, wo = w & 3;                     // wave -> (dst-half, o-quarter)

  // A-staging: thread -> dst_l (0..63), r-half, 2 src rows (sA, sA+4)
  int dst_l = (t >> 1) & 63;
  int rh = (t & 1) * 4;
  int sA = t >> 7;                     // 0..3
  // B-staging: pre-swizzled source chunk
  int csw = (l & 7) ^ (l >> 3);

  const size_t adj_b = (size_t)b << 23;
  const unsigned short* ftb = ft + ((size_t)b << 21);
  const int src_base = kc * 512;

  float dsum = 0.f;
  floatx4 acc[2][2] = {};
  float4 av0[2], av1[2];

  auto A_load = [&](int kt, float4* v) {
#pragma unroll
    for (int j = 0; j < 2; ++j) {
      int src = src_base + kt * 8 + sA + j * 4;
      v[j] = *(const float4*)(adj + adj_b + ((size_t)src << 13)
                              + ((size_t)(dst0 + dst_l) << 3) + rh);
    }
  };
  auto A_store = [&](int buf, const float4* v) {
#pragma unroll
    for (int j = 0; j < 2; ++j) {
      int src_l = sA + j * 4;
      float4 q = v[j];
      dsum += q.x + q.y + q.z + q.w;
      ushortx4 h;
      h[0] = f2bf(q.x); h[1] = f2bf(q.y); h[2] = f2bf(q.z); h[3] = f2bf(q.w);
      int slot = src_l ^ (dst_l & 7);
      *(ushortx4*)&Alds[buf * ASZ + dst_l * 64 + slot * 8 + rh] = h;
    }
  };
  auto B_stage = [&](int kt, int buf) {            // 2 gload16/wave, rows w*16..+15
    int kbase = (src_base + kt * 8) * 8;
#pragma unroll
    for (int i = 0; i < 2; ++i) {
      int orow = w * 16 + i * 8 + (l >> 3);
      const unsigned short* g = ftb + ((size_t)(o0 + orow) << 13) + kbase + (csw << 3);
      gload16(g, &Blds[buf * BSZ + (w * 16 + i * 8) * 64]);
    }
  };
  auto compute = [&](int buf) {
#pragma unroll
    for (int s = 0; s < 2; ++s) {
      int slotbase = s * 4 + lg;
      shortx8 af[2], bfr[2];
#pragma unroll
      for (int mi = 0; mi < 2; ++mi) {
        int arow = wm * 32 + mi * 16 + lr;
        af[mi] = *(const shortx8*)&Alds[buf * ASZ + arow * 64 + ((slotbase ^ (arow & 7)) << 3)];
      }
#pragma unroll
      for (int ni = 0; ni < 2; ++ni) {
        int brow = wo * 32 + ni * 16 + lr;
        bfr[ni] = *(const shortx8*)&Blds[buf * BSZ + brow * 64 + ((slotbase ^ (brow & 7)) << 3)];
      }
#pragma unroll
      for (int mi = 0; mi < 2; ++mi)
#pragma unroll
        for (int ni = 0; ni < 2; ++ni)
          acc[mi][ni] = __builtin_amdgcn_mfma_f32_16x16x32_bf16(af[mi], bfr[ni], acc[mi][ni], 0, 0, 0);
    }
  };

#define STEP(kt, C0, C1, C2, RIN, ROUT, ISS, ST)                       \
  {                                                                    \
    if (ISS) { A_load((kt) + 2, ROUT); B_stage((kt) + 2, C2); }        \
    if (ST)  A_store(C1, RIN);                                         \
    compute(C0);                                                       \
    if (ST) {                                                          \
      if (ISS) { FENCE_KEEP4; } else { FENCE_ALL; }                    \
      __builtin_amdgcn_s_barrier();                                    \
      MEMFENCE;                                                        \
    }                                                                  \
  }

  // ---- prologue: buf0 = kt0 staged; A(1)+B(1) (4 ops) stay in flight ----
  B_stage(0, 0);
  A_load(0, av0);
  A_load(1, av1);
  B_stage(1, 1);
  A_store(0, av0);                     // waits A(0) -> vmcnt(4); B(0) already landed
  FENCE_KEEP4;
  __builtin_amdgcn_s_barrier();
  MEMFENCE;

  // ---- main loop: 60 kt in 10 6-step macro-cycles, all-static indices ----
  for (int kt0 = 0; kt0 < 60; kt0 += 6) {
    STEP(kt0 + 0, 0, 1, 2, av1, av0, 1, 1);
    STEP(kt0 + 1, 1, 2, 0, av0, av1, 1, 1);
    STEP(kt0 + 2, 2, 0, 1, av1, av0, 1, 1);
    STEP(kt0 + 3, 0, 1, 2, av0, av1, 1, 1);
    STEP(kt0 + 4, 1, 2, 0, av1, av0, 1, 1);
    STEP(kt0 + 5, 2, 0, 1, av0, av1, 1, 1);
  }
  // ---- tail: kt = 60..63 ----
  STEP(60, 0, 1, 2, av1, av0, 1, 1);
  STEP(61, 1, 2, 0, av0, av1, 1, 1);
  STEP(62, 2, 0, 1, av1, av0, 0, 1);
  STEP(63, 0, 1, 2, av0, av1, 0, 0);
#undef STEP
  __syncthreads();                     // protect Alds overlay

  // ---- denom reduction (deterministic): 8 partials per dst row ----
  float* dsf = (float*)Alds;
  dsf[t] = dsum;
  __syncthreads();
  if (t < 64) {
    float s = 0.f;
#pragma unroll
    for (int sl = 0; sl < 4; ++sl) {
      s += dsf[sl * 128 + t * 2];
      s += dsf[sl * 128 + t * 2 + 1];
    }
    dpart[kc * 8192 + (b << 10) + dst0 + t] = s;
  }

  // ---- write partials ----
#pragma unroll
  for (int mi = 0; mi < 2; ++mi) {
#pragma unroll
    for (int reg = 0; reg < 4; ++reg) {
      int row = dst0 + wm * 32 + mi * 16 + lg * 4 + reg;
#pragma unroll
      for (int ni = 0; ni < 2; ++ni) {
        int col = o0 + wo * 32 + ni * 16 + lr;
        pout[(size_t)kc * 2097152 + (((size_t)b << 10) + row) * 256 + col] = acc[mi][ni][reg];
      }
    }
  }
}

// ---------------- kernel 3: split-K reduce + normalize ----------------
__global__ __launch_bounds__(256) void k3_reduce(const float* __restrict__ pout,
                                                 const float* __restrict__ dpart,
                                                 float* __restrict__ outp) {
  int bid = blockIdx.x;              // b*1024 + dst
  size_t base = (size_t)bid * 256 + threadIdx.x;
  float v = pout[base] + pout[2097152 + base];
  float d = dpart[bid] + dpart[8192 + bid];
  outp[base] = v / fmaxf(d, 1e-16f);
}

// ---------------- launch ----------------
extern "C" void kernel_launch(void* const* d_in, const int* in_sizes, int n_in,
                              void* d_out, int out_size, void* d_ws, size_t ws_size,
                              hipStream_t stream) {
  const float* x   = (const float*)d_in[0];
  const float* adj = (const float*)d_in[1];
  const float* w   = (const float*)d_in[2];
  float* out = (float*)d_out;

  char* ws = (char*)d_ws;
  unsigned short* ft  = (unsigned short*)(ws);              // 32 MB
  unsigned short* xbf = (unsigned short*)(ws + 33554432);   //  4 MB
  unsigned short* wt  = (unsigned short*)(ws + 37748736);   //  1 MB
  float* pout  = (float*)(ws + 38797312);                   // 16 MB
  float* dpart = (float*)(ws + 55574528);                   // 64 KB

  prep_xw<<<3072, 256, 0, stream>>>(x, w, xbf, wt);
  k1_gemm<<<1024, 256, 0, stream>>>(xbf, wt, ft);
  k2_gemm<<<512, 512, 0, stream>>>(adj, ft, pout, dpart);
  k3_reduce<<<8192, 256, 0, stream>>>(pout, dpart, out);
}